// Round 2
// baseline (502.367 us; speedup 1.0000x reference)
//
#include <hip/hip_runtime.h>

#define H 32

// tanh(x) = 1 - 2/(1 + exp2(x * 2*log2(e))); saturates correctly at +/-inf.
__device__ __forceinline__ float fast_tanh(float x) {
    float e = __builtin_amdgcn_exp2f(x * 2.8853900817779268f);
    float r = __builtin_amdgcn_rcpf(e + 1.0f);
    return fmaf(-2.0f, r, 1.0f);
}

// acc += (quad-lane q's copy of p) * w — one v_fmac_f32_dpp.
// p regs are only written by ds_bpermute (lgkmcnt-guarded) => no VALU->DPP hazard.
#define QFMA(acc, p, w, q) \
    asm("v_fmac_f32_dpp %0, %1, %2 quad_perm:[" #q "," #q "," #q "," #q "] row_mask:0xf bank_mask:0xf" \
        : "+v"(acc) : "v"(p), "v"(w))

// One column i of the mat-vec, round-robin over the 4 accumulators so each
// chain is touched every 4 instrs (8-cycle reuse distance >= FMA latency).
// Per-accumulator summation order is IDENTICAL to the old CH8 (bit-exact).
#define MV4(i) \
    QFMA(a0, p[i], whh[i],      0); \
    QFMA(a1, p[i], whh[8 + i],  1); \
    QFMA(a2, p[i], whh[16 + i], 2); \
    QFMA(a3, p[i], whh[24 + i], 3)

// dpp mov, bound_ctrl=1: shifted-in lanes contribute 0.
#define DPPMOV(x, ctrl) \
    __int_as_float(__builtin_amdgcn_update_dpp(0, __float_as_int(x), (ctrl), 0xf, 0xf, true))
#define ROW_SHR1 0x111
#define ROW_SHR2 0x112
#define ROW_SHR4 0x114

// x-projection: 5 FMAs off broadcast-loaded onehot/reward.
#define XP(oh, rwc) fmaf((oh).x, wih0, fmaf((oh).y, wih1, fmaf((oh).z, wih2, \
                     fmaf((oh).w, wih3, fmaf((rwc), wih4, bias)))))

__global__ __launch_bounds__(256, 1) void rnn_fused(
    const float* __restrict__ onehot,   // [B,T,4]
    const float* __restrict__ rewards,  // [B,T]
    const float* __restrict__ W_ih,     // [H,5]
    const float* __restrict__ W_hh,     // [H,H]
    const float* __restrict__ b_ih,     // [H]
    const float* __restrict__ b_hh,     // [H]
    const float* __restrict__ W_ro,     // [4,H]
    const float* __restrict__ b_ro,     // [4]
    float* __restrict__ out_logits,     // [B,T,4]
    float* __restrict__ out_hT,         // [B,H]
    int T)
{
    const int tid = threadIdx.x;
    const int wl  = tid & 63;
    // Upper wave half parked: the 32 active lanes time-interleave TWO batches
    // (software 2-thread) so each recurrence's bpermute+tanh latency is hidden
    // under the other's FMA block. Dead half-pass may also be skipped by HW.
    if (wl >= 32) return;

    const int u   = tid & 31;            // hidden unit owned by this lane
    const int grp = blockIdx.x * 4 + (tid >> 6);   // global wave id (4 waves/block)
    const int ba  = grp * 2;             // batch "A"
    const int bb  = ba + 1;              // batch "B"
    const int qp  = u & 3;               // quad position -> which 8-chunk we gather
    const int r   = u >> 3;              // readout row this lane contributes to
    const bool hi = ((u >> 2) & 1) != 0; // which half of our chunk for readout
    const bool writer = (u & 7) == 7;    // lane that stores logit row r

    // bpermute byte-indices for our 8-chunk (active lanes are all < 32)
    const int ib = (8 * qp) << 2;
    const int idx0 = ib +  0, idx1 = ib +  4, idx2 = ib +  8, idx3 = ib + 12;
    const int idx4 = ib + 16, idx5 = ib + 20, idx6 = ib + 24, idx7 = ib + 28;

    // ---- persistent per-lane weights (shared by both batches) ----
    float whh[H];
#pragma unroll
    for (int k = 0; k < 8; ++k) {
        float4 w = *(const float4*)(W_hh + u * H + 4 * k);
        whh[4*k+0] = w.x; whh[4*k+1] = w.y; whh[4*k+2] = w.z; whh[4*k+3] = w.w;
    }
    const float wih0 = W_ih[u*5+0], wih1 = W_ih[u*5+1], wih2 = W_ih[u*5+2],
                wih3 = W_ih[u*5+3], wih4 = W_ih[u*5+4];
    const float bias = b_ih[u] + b_hh[u];
    const float4 wr4 = *(const float4*)(W_ro + r * H + qp * 8 + (hi ? 4 : 0));
    const float bro = b_ro[r];

    const float* ohA = onehot  + (size_t)ba * T * 4;
    const float* rwA = rewards + (size_t)ba * T;
    float*       lgA = out_logits + (size_t)ba * T * 4;
    const float* ohB = onehot  + (size_t)bb * T * 4;
    const float* rwB = rewards + (size_t)bb * T;
    float*       lgB = out_logits + (size_t)bb * T * 4;

    // ---- 4-step-deep x prefetch rings (one per batch) ----
    float4 oA0 = *(const float4*)(ohA + 0), oA1 = *(const float4*)(ohA + 4),
           oA2 = *(const float4*)(ohA + 8), oA3 = *(const float4*)(ohA + 12);
    float4 rAv = *(const float4*)(rwA);
    float4 oB0 = *(const float4*)(ohB + 0), oB1 = *(const float4*)(ohB + 4),
           oB2 = *(const float4*)(ohB + 8), oB3 = *(const float4*)(ohB + 12);
    float4 rBv = *(const float4*)(rwB);

    float hA, hB;                        // running hidden state (per batch)
    float pA0[8], pA1[8], pB0[8], pB1[8];// double-buffered gathered chunks

    auto gather = [&](float (&d)[8], float h) {
        const int hb = __float_as_int(h);
        d[0] = __int_as_float(__builtin_amdgcn_ds_bpermute(idx0, hb));
        d[1] = __int_as_float(__builtin_amdgcn_ds_bpermute(idx1, hb));
        d[2] = __int_as_float(__builtin_amdgcn_ds_bpermute(idx2, hb));
        d[3] = __int_as_float(__builtin_amdgcn_ds_bpermute(idx3, hb));
        d[4] = __int_as_float(__builtin_amdgcn_ds_bpermute(idx4, hb));
        d[5] = __int_as_float(__builtin_amdgcn_ds_bpermute(idx5, hb));
        d[6] = __int_as_float(__builtin_amdgcn_ds_bpermute(idx6, hb));
        d[7] = __int_as_float(__builtin_amdgcn_ds_bpermute(idx7, hb));
    };

    auto readout = [&](const float (&p)[8], float* __restrict__ lg, int t) {
        float s0 = hi ? p[4] : p[0];
        float s1 = hi ? p[5] : p[1];
        float s2 = hi ? p[6] : p[2];
        float s3 = hi ? p[7] : p[3];
        float s = fmaf(s3, wr4.w, fmaf(s2, wr4.z, fmaf(s1, wr4.y, s0 * wr4.x)));
        s += DPPMOV(s, ROW_SHR1);
        s += DPPMOV(s, ROW_SHR2);
        s += DPPMOV(s, ROW_SHR4);        // lane (8r+7) holds full dot of row r
        if (writer) lg[(size_t)t * 4 + r] = s + bro;
    };

    auto mv = [&](const float (&p)[8], float xp) -> float {
        float a0 = xp, a1 = 0.f, a2 = 0.f, a3 = 0.f;
        MV4(0); MV4(1); MV4(2); MV4(3); MV4(4); MV4(5); MV4(6); MV4(7);
        return fast_tanh((a0 + a1) + (a2 + a3));
    };

    // One macro time step t for BOTH recurrences, phase-interleaved so each
    // gather's ~100-cycle latency is covered by the other batch's mat-vec.
    // Entry invariant: hA = h_A^{t-1}; pBo = gather(h_B^{t-1}).
    auto mstep = [&](float (&pAn)[8], const float (&pAo)[8],
                     float (&pBn)[8], const float (&pBo)[8],
                     float xpA, float xpB, int t, bool roA, bool roB) {
        gather(pAn, hA);                       // issue: gather h_A^{t-1}
        if (roA) readout(pAo, lgA, t - 2);     // filler: logits_A[t-2]
        hB = mv(pBo, xpB);                     // h_B^t   (covers gather A)
        gather(pBn, hB);                       // issue: gather h_B^t
        if (roB) readout(pBo, lgB, t - 1);     // filler: logits_B[t-1]
        hA = mv(pAn, xpA);                     // h_A^t   (covers gather B)
    };

    // ---- prologue: t = 0..3 ----
    {
        float xA0 = XP(oA0, rAv.x), xA1 = XP(oA1, rAv.y),
              xA2 = XP(oA2, rAv.z), xA3 = XP(oA3, rAv.w);
        float xB0 = XP(oB0, rBv.x), xB1 = XP(oB1, rBv.y),
              xB2 = XP(oB2, rBv.z), xB3 = XP(oB3, rBv.w);
        oA0 = *(const float4*)(ohA + 16); oA1 = *(const float4*)(ohA + 20);
        oA2 = *(const float4*)(ohA + 24); oA3 = *(const float4*)(ohA + 28);
        rAv = *(const float4*)(rwA + 4);
        oB0 = *(const float4*)(ohB + 16); oB1 = *(const float4*)(ohB + 20);
        oB2 = *(const float4*)(ohB + 24); oB3 = *(const float4*)(ohB + 28);
        rBv = *(const float4*)(rwB + 4);

        // t = 0: h^{-1} = 0 -> no mat-vec needed
        hA = fast_tanh(xA0);
        hB = fast_tanh(xB0);
        gather(pB0, hB);                       // parity-0 gather of h_B^0
        // t = 1..3 (readouts come online as buffers fill)
        mstep(pA1, pA0, pB1, pB0, xA1, xB1, 1, false, true);
        mstep(pA0, pA1, pB0, pB1, xA2, xB2, 2, true,  true);
        mstep(pA1, pA0, pB1, pB0, xA3, xB3, 3, true,  true);
    }

    // ---- steady state: 4 macro steps per iteration ----
    for (int tb = 4; tb < T; tb += 4) {
        float xA0 = XP(oA0, rAv.x), xA1 = XP(oA1, rAv.y),
              xA2 = XP(oA2, rAv.z), xA3 = XP(oA3, rAv.w);
        float xB0 = XP(oB0, rBv.x), xB1 = XP(oB1, rBv.y),
              xB2 = XP(oB2, rBv.z), xB3 = XP(oB3, rBv.w);
        if (tb + 4 < T) {
            oA0 = *(const float4*)(ohA + (size_t)(tb + 4) * 4);
            oA1 = *(const float4*)(ohA + (size_t)(tb + 5) * 4);
            oA2 = *(const float4*)(ohA + (size_t)(tb + 6) * 4);
            oA3 = *(const float4*)(ohA + (size_t)(tb + 7) * 4);
            rAv = *(const float4*)(rwA + tb + 4);
            oB0 = *(const float4*)(ohB + (size_t)(tb + 4) * 4);
            oB1 = *(const float4*)(ohB + (size_t)(tb + 5) * 4);
            oB2 = *(const float4*)(ohB + (size_t)(tb + 6) * 4);
            oB3 = *(const float4*)(ohB + (size_t)(tb + 7) * 4);
            rBv = *(const float4*)(rwB + tb + 4);
        }
        mstep(pA0, pA1, pB0, pB1, xA0, xB0, tb + 0, true, true);
        mstep(pA1, pA0, pB1, pB0, xA1, xB1, tb + 1, true, true);
        mstep(pA0, pA1, pB0, pB1, xA2, xB2, tb + 2, true, true);
        mstep(pA1, pA0, pB1, pB0, xA3, xB3, tb + 3, true, true);
    }

    // ---- epilogue (last loop step was t = T-1, parity 1) ----
    readout(pA1, lgA, T - 2);                  // h_A^{T-2}
    gather(pA0, hA);                           // gather h_A^{T-1}
    readout(pB1, lgB, T - 1);                  // h_B^{T-1} (fills gather latency)
    readout(pA0, lgA, T - 1);                  // h_A^{T-1}
    out_hT[(size_t)ba * H + u] = hA;
    out_hT[(size_t)bb * H + u] = hB;
}

extern "C" void kernel_launch(void* const* d_in, const int* in_sizes, int n_in,
                              void* d_out, int out_size, void* d_ws, size_t ws_size,
                              hipStream_t stream) {
    const float* onehot  = (const float*)d_in[0];
    const float* rewards = (const float*)d_in[1];
    const float* W_ih    = (const float*)d_in[2];
    const float* W_hh    = (const float*)d_in[3];
    const float* b_ih    = (const float*)d_in[4];
    const float* b_hh    = (const float*)d_in[5];
    const float* W_ro    = (const float*)d_in[6];
    const float* b_ro    = (const float*)d_in[7];

    const int T = 1024;                  // per setup_inputs()
    const int B = in_sizes[1] / T;       // in_sizes[1] = B*T

    float* out_logits = (float*)d_out;                        // [B,T,4]
    float* out_hT     = (float*)d_out + (size_t)B * T * 4;    // [B,H]

    dim3 block(256);                     // 4 waves/block; 2 batches per wave (lower half)
    dim3 grid(B / 8);                    // 256 blocks -> 1024 waves -> 1 wave/SIMD
    rnn_fused<<<grid, block, 0, stream>>>(onehot, rewards, W_ih, W_hh,
                                          b_ih, b_hh, W_ro, b_ro,
                                          out_logits, out_hT, T);
}

// Round 4
// 307.175 us; speedup vs baseline: 1.6354x; 1.6354x over previous
//
#include <hip/hip_runtime.h>

#define H 32
#define GPB 8   // 32-lane groups per 256-thread block

// tanh(x) = 1 - 2/(1 + exp2(x * 2*log2(e))); saturates correctly at +/-inf.
__device__ __forceinline__ float fast_tanh(float x) {
    float e = __builtin_amdgcn_exp2f(x * 2.8853900817779268f);
    float r = __builtin_amdgcn_rcpf(e + 1.0f);
    return fmaf(-2.0f, r, 1.0f);
}

// acc += (quad-lane q's copy of p) * w — one v_fmac_f32_dpp.
// p regs are only written by ds_bpermute (lgkmcnt-guarded) => no VALU->DPP hazard.
#define QFMA(acc, p, w, q) \
    asm("v_fmac_f32_dpp %0, %1, %2 quad_perm:[" #q "," #q "," #q "," #q "] row_mask:0xf bank_mask:0xf" \
        : "+v"(acc) : "v"(p), "v"(w))

// Column i of the mat-vec: round-robin over the 4 accumulators so each chain
// is touched every 4 instructions (8-cycle reuse distance >= FMA latency =>
// no dependency bubbles). Per-accumulator summation order is IDENTICAL to the
// old serial CH8 (bit-exact), only the instruction interleave changes.
#define MV4(i) \
    QFMA(a0, p[i], whh[i],      0); \
    QFMA(a1, p[i], whh[8 + i],  1); \
    QFMA(a2, p[i], whh[16 + i], 2); \
    QFMA(a3, p[i], whh[24 + i], 3)

// dpp mov, bound_ctrl=1: shifted-in lanes contribute 0.
#define DPPMOV(x, ctrl) \
    __int_as_float(__builtin_amdgcn_update_dpp(0, __float_as_int(x), (ctrl), 0xf, 0xf, true))
#define ROW_SHR1 0x111
#define ROW_SHR2 0x112
#define ROW_SHR4 0x114

// x-projection: 5 FMAs off broadcast-loaded onehot/reward.
#define XP(oh, rwc) fmaf((oh).x, wih0, fmaf((oh).y, wih1, fmaf((oh).z, wih2, \
                     fmaf((oh).w, wih3, fmaf((rwc), wih4, bias)))))

__global__ __launch_bounds__(256, 1) void rnn_fused(
    const float* __restrict__ onehot,   // [B,T,4]
    const float* __restrict__ rewards,  // [B,T]
    const float* __restrict__ W_ih,     // [H,5]
    const float* __restrict__ W_hh,     // [H,H]
    const float* __restrict__ b_ih,     // [H]
    const float* __restrict__ b_hh,     // [H]
    const float* __restrict__ W_ro,     // [4,H]
    const float* __restrict__ b_ro,     // [4]
    float* __restrict__ out_logits,     // [B,T,4]
    float* __restrict__ out_hT,         // [B,H]
    int T)
{
    const int tid = threadIdx.x;
    const int u   = tid & 31;            // hidden unit owned by this lane
    const int wl  = tid & 63;            // lane within the wave64
    const int b   = blockIdx.x * GPB + (tid >> 5);
    const int qp  = u & 3;               // quad position -> which 8-chunk we gather
    const int r   = u >> 3;              // readout row this lane contributes to
    const bool hi = ((u >> 2) & 1) != 0; // which half of our chunk for readout
    const bool writer = (u & 7) == 7;    // lane that stores logit row r

    // bpermute byte-indices for our 8-chunk: lane (groupbase + 8*qp + i)
    const int ib = ((wl & 32) + 8 * qp) << 2;
    const int idx0 = ib +  0, idx1 = ib +  4, idx2 = ib +  8, idx3 = ib + 12;
    const int idx4 = ib + 16, idx5 = ib + 20, idx6 = ib + 24, idx7 = ib + 28;

    // ---- persistent per-lane weights ----
    float whh[H];
#pragma unroll
    for (int k = 0; k < 8; ++k) {
        float4 w = *(const float4*)(W_hh + u * H + 4 * k);
        whh[4*k+0] = w.x; whh[4*k+1] = w.y; whh[4*k+2] = w.z; whh[4*k+3] = w.w;
    }
    const float wih0 = W_ih[u*5+0], wih1 = W_ih[u*5+1], wih2 = W_ih[u*5+2],
                wih3 = W_ih[u*5+3], wih4 = W_ih[u*5+4];
    const float bias = b_ih[u] + b_hh[u];
    const float4 wr4 = *(const float4*)(W_ro + r * H + qp * 8 + (hi ? 4 : 0));
    const float bro = b_ro[r];

    const float* oh_ptr = onehot  + (size_t)b * T * 4;
    const float* rw_ptr = rewards + (size_t)b * T;
    float*       lg_ptr = out_logits + (size_t)b * T * 4;

    // ---- two input-register banks (X: oh0..3/rwv, Y: qh0..3/qrw) so the
    //      x-projection can be computed INSIDE each step (gather-latency
    //      filler) without being clobbered by the next prefetch ----
    float4 oh0, oh1, oh2, oh3, rwv;
    float4 qh0, qh1, qh2, qh3, qrw;

    auto loadX = [&](int t) {
        oh0 = *(const float4*)(oh_ptr + (size_t)t * 4);
        oh1 = *(const float4*)(oh_ptr + (size_t)(t + 1) * 4);
        oh2 = *(const float4*)(oh_ptr + (size_t)(t + 2) * 4);
        oh3 = *(const float4*)(oh_ptr + (size_t)(t + 3) * 4);
        rwv = *(const float4*)(rw_ptr + t);
    };
    auto loadY = [&](int t) {
        qh0 = *(const float4*)(oh_ptr + (size_t)t * 4);
        qh1 = *(const float4*)(oh_ptr + (size_t)(t + 1) * 4);
        qh2 = *(const float4*)(oh_ptr + (size_t)(t + 2) * 4);
        qh3 = *(const float4*)(oh_ptr + (size_t)(t + 3) * 4);
        qrw = *(const float4*)(rw_ptr + t);
    };

    float hj = 0.0f;                     // h^{(-1)} = 0
    float pA[8], pB[8];                  // double-buffered gathered chunk

    // logits_t from a gathered h^{(t)} chunk buffer
    auto readout = [&](const float (&p)[8], int t) {
        float s0 = hi ? p[4] : p[0];
        float s1 = hi ? p[5] : p[1];
        float s2 = hi ? p[6] : p[2];
        float s3 = hi ? p[7] : p[3];
        float s = fmaf(s3, wr4.w, fmaf(s2, wr4.z, fmaf(s1, wr4.y, s0 * wr4.x)));
        s += DPPMOV(s, ROW_SHR1);
        s += DPPMOV(s, ROW_SHR2);
        s += DPPMOV(s, ROW_SHR4);        // lane (8r+7) holds full dot of row r
        if (writer) lg_ptr[(size_t)t * 4 + r] = s + bro;
    };

    // One recurrence step. Gather of h^{(t-1)} is issued first; readout of
    // h^{(t-2)} plus the x-projection fill the bpermute latency; then the
    // bubble-free round-robin mat-vec and tanh.
    auto step = [&](float (&pN)[8], const float (&pO)[8],
                    const float4& oh, float rwc, int t, bool ro) {
        const int hb = __float_as_int(hj);
        pN[0] = __int_as_float(__builtin_amdgcn_ds_bpermute(idx0, hb));
        pN[1] = __int_as_float(__builtin_amdgcn_ds_bpermute(idx1, hb));
        pN[2] = __int_as_float(__builtin_amdgcn_ds_bpermute(idx2, hb));
        pN[3] = __int_as_float(__builtin_amdgcn_ds_bpermute(idx3, hb));
        pN[4] = __int_as_float(__builtin_amdgcn_ds_bpermute(idx4, hb));
        pN[5] = __int_as_float(__builtin_amdgcn_ds_bpermute(idx5, hb));
        pN[6] = __int_as_float(__builtin_amdgcn_ds_bpermute(idx6, hb));
        pN[7] = __int_as_float(__builtin_amdgcn_ds_bpermute(idx7, hb));
        if (ro) readout(pO, t - 2);      // latency filler (depends only on pO)
        const float xp = XP(oh, rwc);    // more filler (prefetched regs only)
        float (&p)[8] = pN;
        float a0 = xp, a1 = 0.f, a2 = 0.f, a3 = 0.f;
        MV4(0); MV4(1); MV4(2); MV4(3); MV4(4); MV4(5); MV4(6); MV4(7);
        hj = fast_tanh((a0 + a1) + (a2 + a3));
    };

    // ---- prologue: banks X=(t 0..3), Y=(t 4..7); steps 0..7 peeled ----
    loadX(0);
    loadY(4);
    step(pA, pB, oh0, rwv.x, 0, false);
    step(pB, pA, oh1, rwv.y, 1, false);
    step(pA, pB, oh2, rwv.z, 2, true);
    step(pB, pA, oh3, rwv.w, 3, true);
    loadX(8);                            // refill X for t = 8..11
    step(pA, pB, qh0, qrw.x, 4, true);
    step(pB, pA, qh1, qrw.y, 5, true);
    step(pA, pB, qh2, qrw.z, 6, true);
    step(pB, pA, qh3, qrw.w, 7, true);

    // ---- steady state: 8 steps per iteration, banks ping-pong ----
    for (int tb = 8; tb < T; tb += 8) {
        if (tb + 4 < T) loadY(tb + 4);   // refill Y while X block runs
        step(pA, pB, oh0, rwv.x, tb + 0, true);
        step(pB, pA, oh1, rwv.y, tb + 1, true);
        step(pA, pB, oh2, rwv.z, tb + 2, true);
        step(pB, pA, oh3, rwv.w, tb + 3, true);
        if (tb + 8 < T) loadX(tb + 8);   // refill X while Y block runs
        step(pA, pB, qh0, qrw.x, tb + 4, true);
        step(pB, pA, qh1, qrw.y, tb + 5, true);
        step(pA, pB, qh2, qrw.z, tb + 6, true);
        step(pB, pA, qh3, qrw.w, tb + 7, true);
    }

    // ---- epilogue (last step was t = T-1, wrote pB = gather(h^{T-2})) ----
    readout(pB, T - 2);
    {
        const int hb = __float_as_int(hj);   // hj = h^{(T-1)}
        pA[0] = __int_as_float(__builtin_amdgcn_ds_bpermute(idx0, hb));
        pA[1] = __int_as_float(__builtin_amdgcn_ds_bpermute(idx1, hb));
        pA[2] = __int_as_float(__builtin_amdgcn_ds_bpermute(idx2, hb));
        pA[3] = __int_as_float(__builtin_amdgcn_ds_bpermute(idx3, hb));
        pA[4] = __int_as_float(__builtin_amdgcn_ds_bpermute(idx4, hb));
        pA[5] = __int_as_float(__builtin_amdgcn_ds_bpermute(idx5, hb));
        pA[6] = __int_as_float(__builtin_amdgcn_ds_bpermute(idx6, hb));
        pA[7] = __int_as_float(__builtin_amdgcn_ds_bpermute(idx7, hb));
    }
    readout(pA, T - 1);                  // logits_{T-1} from h^{(T-1)}
    out_hT[(size_t)b * H + u] = hj;      // h_T
}

extern "C" void kernel_launch(void* const* d_in, const int* in_sizes, int n_in,
                              void* d_out, int out_size, void* d_ws, size_t ws_size,
                              hipStream_t stream) {
    const float* onehot  = (const float*)d_in[0];
    const float* rewards = (const float*)d_in[1];
    const float* W_ih    = (const float*)d_in[2];
    const float* W_hh    = (const float*)d_in[3];
    const float* b_ih    = (const float*)d_in[4];
    const float* b_hh    = (const float*)d_in[5];
    const float* W_ro    = (const float*)d_in[6];
    const float* b_ro    = (const float*)d_in[7];

    const int T = 1024;                  // per setup_inputs()
    const int B = in_sizes[1] / T;       // in_sizes[1] = B*T

    float* out_logits = (float*)d_out;                        // [B,T,4]
    float* out_hT     = (float*)d_out + (size_t)B * T * 4;    // [B,H]

    dim3 block(256);                     // 4 waves/block, 1024 waves total
    dim3 grid(B / GPB);                  // = 256 blocks -> 1 wave/SIMD chip-wide
    rnn_fused<<<grid, block, 0, stream>>>(onehot, rewards, W_ih, W_hh,
                                          b_ih, b_hh, W_ro, b_ro,
                                          out_logits, out_hT, T);
}